// Round 9
// baseline (485.229 us; speedup 1.0000x reference)
//
#include <hip/hip_runtime.h>

// Hungarian (e-maxx shortest-augmenting-path), 32 independent 128x128 L1
// assignment problems. ONE WAVE per problem, 2 columns per lane, zero LDS,
// zero barriers, bit-exact fp trajectory vs the JAX reference.
//
// R8 WIN (561->494): fused v_min_f32_dpp reduction. R9 WIN (494->466):
// ty-poisoning. R10 FAILED (466->1031): wave is ISSUE-bound (1 instr/cy,
// wave64 VALU=2cy) — never add a second instruction stream. R11 NEUTRAL:
// SALU co-issues free in VALU gap cycles. R12 WIN (468->398): fill the
// reduce's DPP-hazard slots with body VALU (way/w/u_row updates).
// R13: SGPR-mask bookkeeping — convert mark/update machinery from VALU to
// SALU masks + exec-masked ops:
//   * winner mask from the argmin ballot itself: bit=1<<src; mk0m=hi?0:bit;
//     mk1m=hi?bit:0 (SALU). Poisons = v_cndmask with SGPR-pair mask
//     (kills 2 v_cmp_eq).
//   * used-masks u0m/u1m as SGPRs (u|=mk, SALU). Dual update w+=td,v-=td
//     becomes 4 VALU under s_mov exec,u0m/u1m (saveexec pattern) — bitwise
//     identical (masked-off lanes computed x+-0.0 before; +-0 cases checked).
//     Kills vdelta mov + 2 td-cndmasks + 3 lag-copies; w back to lag-0
//     (reference order).
//   * cc-cmps (cur<minv_old) move into two reduce slots (v_cmp_lt writing
//     SGPR pairs), displacing the departed w-adds; u_row add stays slotted
//     with a direct SGPR operand.
// fp value sequence bit-identical to R12/reference by construction.
// (R13 resubmit: previous round hit GPUAcquisitionTimeout — never benched.)

#define NN 128
#define BIGF 1e9f
#define TYBIG 1e13f

__device__ __forceinline__ int rl_i(int x, int l) {
    return __builtin_amdgcn_readlane(x, l);
}
__device__ __forceinline__ float rl_f(float x, int l) {
    return __uint_as_float((uint32_t)__builtin_amdgcn_readlane((int)__float_as_uint(x), l));
}

// full-wave f32 min -> uniform SGPR result (entry step only).
__device__ __forceinline__ float wave_min_f(float x) {
    int d;
    asm("s_nop 1\n\t"
        "v_min_f32_dpp %1, %1, %1 row_shr:1 row_mask:0xf bank_mask:0xf\n\t"
        "s_nop 1\n\t"
        "v_min_f32_dpp %1, %1, %1 row_shr:2 row_mask:0xf bank_mask:0xf\n\t"
        "s_nop 1\n\t"
        "v_min_f32_dpp %1, %1, %1 row_shr:4 row_mask:0xf bank_mask:0xf\n\t"
        "s_nop 1\n\t"
        "v_min_f32_dpp %1, %1, %1 row_shr:8 row_mask:0xf bank_mask:0xf\n\t"
        "s_nop 1\n\t"
        "v_min_f32_dpp %1, %1, %1 row_bcast:15 row_mask:0xa bank_mask:0xf\n\t"
        "s_nop 1\n\t"
        "v_min_f32_dpp %1, %1, %1 row_bcast:31 row_mask:0xc bank_mask:0xf\n\t"
        "s_nop 1\n\t"
        "v_readlane_b32 %0, %1, 63"
        : "=s"(d), "+v"(x));
    return __uint_as_float((uint32_t)d);
}

// Reduction with hazard slots filled:
//   slot0: vj0 = j0 broadcast (covers m-write->DPP hazard)
//   slot1: cc0 = cur0 < minv0_old   (SGPR-pair dest)
//   slot2: cc1 = cur1 < minv1_old
//   slot3: u_row += sdeltap (lag-1, SGPR operand)
//   slot4: way0 = cc0 ? vj0 : way0  (>=3 VALU after cc0 write)
//   slot5: way1 = cc1 ? vj0 : way1
// Fillers never touch the DPP register m. Returns delta in SGPR.
__device__ __forceinline__ float wave_min_fill2(
    float m, int j0,
    float cur0, float cur1, float minv0_old, float minv1_old,
    int& way0, int& way1, float& u_row, float sdeltap)
{
    int d, vj0;
    unsigned long long cc0, cc1;
    asm("v_mov_b32 %2, %8\n\t"
        "v_min_f32_dpp %1, %1, %1 row_shr:1 row_mask:0xf bank_mask:0xf\n\t"
        "v_cmp_lt_f32 %6, %9, %11\n\t"
        "v_min_f32_dpp %1, %1, %1 row_shr:2 row_mask:0xf bank_mask:0xf\n\t"
        "v_cmp_lt_f32 %7, %10, %12\n\t"
        "v_min_f32_dpp %1, %1, %1 row_shr:4 row_mask:0xf bank_mask:0xf\n\t"
        "v_add_f32 %5, %13, %5\n\t"
        "v_min_f32_dpp %1, %1, %1 row_shr:8 row_mask:0xf bank_mask:0xf\n\t"
        "v_cndmask_b32 %3, %3, %2, %6\n\t"
        "v_min_f32_dpp %1, %1, %1 row_bcast:15 row_mask:0xa bank_mask:0xf\n\t"
        "v_cndmask_b32 %4, %4, %2, %7\n\t"
        "v_min_f32_dpp %1, %1, %1 row_bcast:31 row_mask:0xc bank_mask:0xf\n\t"
        "s_nop 1\n\t"
        "v_readlane_b32 %0, %1, 63"
        : "=s"(d), "+v"(m), "=&v"(vj0), "+v"(way0), "+v"(way1), "+v"(u_row),
          "=&s"(cc0), "=&s"(cc1)
        : "s"(j0), "v"(cur0), "v"(cur1), "v"(minv0_old), "v"(minv1_old),
          "s"(sdeltap));
    return __uint_as_float((uint32_t)d);
}

// x = mask ? big : x (v_cndmask with SGPR-pair mask; big pre-hoisted VGPR)
__device__ __forceinline__ void poison(float& x, float big, unsigned long long mk) {
    asm("v_cndmask_b32 %0, %0, %1, %2" : "+v"(x) : "v"(big), "s"(mk));
}

// exec-masked dual update: lanes in u0m: {w0+=d, v0-=d}; in u1m: {w1+=d, v1-=d}
__device__ __forceinline__ void dual_update(
    float& w0, float& v0, float& w1, float& v1,
    unsigned long long u0m, unsigned long long u1m, float sdelta)
{
    unsigned long long sv;
    asm volatile(
        "s_mov_b64 %[sv], exec\n\t"
        "s_mov_b64 exec, %[m0]\n\t"
        "v_add_f32 %[w0], %[sd], %[w0]\n\t"
        "v_sub_f32 %[v0], %[v0], %[sd]\n\t"
        "s_mov_b64 exec, %[m1]\n\t"
        "v_add_f32 %[w1], %[sd], %[w1]\n\t"
        "v_sub_f32 %[v1], %[v1], %[sd]\n\t"
        "s_mov_b64 exec, %[sv]"
        : [sv]"=&s"(sv), [w0]"+v"(w0), [v0]"+v"(v0), [w1]"+v"(w1), [v1]"+v"(v1)
        : [m0]"s"(u0m), [m1]"s"(u1m), [sd]"s"(sdelta));
}

__global__ __launch_bounds__(64) void hungarian_kernel(
    const float* __restrict__ preds,
    const float* __restrict__ targets,
    int* __restrict__ out)
{
    const int prob = blockIdx.x;
    const int lane = threadIdx.x;

    const float2* p2 = (const float2*)preds + prob * NN;
    const float2* t2 = (const float2*)targets + prob * NN;

    float2 qav = p2[lane], qbv = p2[lane + 64];
    float2 tav = t2[lane], tbv = t2[lane + 64];
    const float qrx0 = qav.x, qrx1 = qbv.x;
    const float qry0 = qav.y, qry1 = qbv.y;
    const float tx0  = tav.x, tx1  = tbv.x;
    const float ty0  = tav.y, ty1  = tbv.y;

    float v0 = 0.f, v1 = 0.f;       // column duals (reference: start 0)
    float w0 = 0.f, w1 = 0.f;       // u[p[col]] cache (valid when matched)
    float qcx0 = 0.f, qcx1 = 0.f;   // pred x of row p[col]
    float qcy0 = 0.f, qcy1 = 0.f;   // pred y of row p[col]
    int   p0 = 0, p1 = 0;           // matched row (1-indexed), 0 = free
    const int col0 = lane + 1, col1 = lane + 65;

    // hoisted poison constants in VGPRs (VOP3 cndmask can't take literals,
    // and the mask operand uses the single allowed SGPR read)
    float vBIG = BIGF, vTYBIG = TYBIG;
    asm("" : "+v"(vBIG), "+v"(vTYBIG));

    // free-column masks: bit (c-1) of fm0 for cols 1..64, (c-65) of fm1
    unsigned long long fm0 = ~0ull, fm1 = ~0ull;

    for (int i = 0; i < NN; ++i) {
        // coords of current row i (uniform): stable-source readlanes + cselect
        const float qxa = rl_f(qrx0, i & 63), qxb = rl_f(qrx1, i & 63);
        const float qya = rl_f(qry0, i & 63), qyb = rl_f(qry1, i & 63);
        const float qix = (i & 64) ? qxb : qxa;
        const float qiy = (i & 64) ? qyb : qya;

        // ---- specialized first search step: j0 = 0, nothing used ----
        float minv0 = (fabsf(qix - tx0) + fabsf(qiy - ty0)) - v0;
        float minv1 = (fabsf(qix - tx1) + fabsf(qiy - ty1)) - v1;
        int   way0 = 0, way1 = 0;
        float typ0 = ty0, typ1 = ty1;   // poisonable targets-y (reset per row)
        unsigned long long u0m = 0ull, u1m = 0ull;   // used-column masks

        float m     = fminf(minv0, minv1);
        float delta = wave_min_f(m);
        unsigned long long b0 = __ballot(minv0 == delta);
        unsigned long long b1 = __ballot(minv1 == delta);
        bool hi  = (b0 == 0);
        int  src = (int)__ffsll((long long)(hi ? b1 : b0)) - 1;
        int  j1  = src + (hi ? 65 : 1);

        {
            // winner free? (scalar bit test)
            bool freeWin = (((hi ? fm1 : fm0) >> src) & 1ull) != 0;
            // stable-source fetch of matched-row data of winner column
            float u_j0 = rl_f(hi ? w1 : w0, src);
            float cqx  = rl_f(hi ? qcx1 : qcx0, src);
            float cqy  = rl_f(hi ? qcy1 : qcy0, src);

            // step-0 updates: nothing used -> v,w unchanged; minv -= delta
            minv0 -= delta;
            minv1 -= delta;
            float u_row   = delta;        // u[i+1] = 0 + delta (exact)
            float sdeltap = 0.f;          // lag-1 pending for u_row slot-add
            int   j0      = j1;

            if (!freeWin) {
                for (int it = 0; it < NN + 2; ++it) {
                    // mark used[j0]: winner mask straight from the ballot
                    // (bit src of half hi) — pure SALU.
                    const unsigned long long bit = 1ull << src;
                    const unsigned long long mk0m = hi ? 0ull : bit;
                    const unsigned long long mk1m = hi ? bit : 0ull;
                    u0m |= mk0m; u1m |= mk1m;
                    poison(minv0, vBIG,   mk0m);
                    poison(minv1, vBIG,   mk1m);
                    poison(typ0,  vTYBIG, mk0m);
                    poison(typ1,  vTYBIG, mk1m);

                    // used cols: cur == 1e13 exactly (> any minv); unused:
                    // bit-exact reference reduced cost
                    const float cur0 = ((fabsf(cqx - tx0) + fabsf(cqy - typ0)) - u_j0) - v0;
                    const float cur1 = ((fabsf(cqx - tx1) + fabsf(cqy - typ1)) - u_j0) - v1;

                    // minv update (pre-update copies live into the reduce
                    // for the slotted cc-compares)
                    const float m0o = minv0, m1o = minv1;
                    minv0 = fminf(cur0, minv0);
                    minv1 = fminf(cur1, minv1);
                    m = fminf(minv0, minv1);

                    // reduce; slots do: cc=(cur<minv_old), way cndmasks,
                    // u_row += sdeltap
                    delta = wave_min_fill2(m, j0, cur0, cur1, m0o, m1o,
                                           way0, way1, u_row, sdeltap);

                    b0 = __ballot(minv0 == delta);
                    b1 = __ballot(minv1 == delta);
                    hi  = (b0 == 0);
                    src = (int)__ffsll((long long)(hi ? b1 : b0)) - 1;
                    j1  = src + (hi ? 65 : 1);

                    // terminate if winner is a free column (scalar bit test)
                    const bool term = (((hi ? fm1 : fm0) >> src) & 1ull) != 0;
                    const float u_nn = rl_f(hi ? w1 : w0, src);
                    const float nqx  = rl_f(hi ? qcx1 : qcx0, src);
                    const float nqy  = rl_f(hi ? qcy1 : qcy0, src);

                    // reference-exact dual updates under exec masks
                    // (lag-0 = reference order; masked-off lanes previously
                    // computed x+-0.0 which is bitwise identical)
                    dual_update(w0, v0, w1, v1, u0m, u1m, delta);
                    minv0 -= delta;
                    minv1 -= delta;
                    sdeltap = delta;      // u_row picks it up next slot/flush

                    j0 = j1; u_j0 = u_nn; cqx = nqx; cqy = nqy;
                    if (term) break;
                }

                // flush the final iteration's pending u_row add
                u_row += sdeltap;
            }

            // the terminating col j0 leaves the free set (once per row)
            {
                const unsigned long long mkb = 1ull << ((j0 - 1) & 63);
                if (j0 > 64) fm1 &= ~mkb; else fm0 &= ~mkb;
            }

            // ---- augment: shuffle (p, w, qc) along `way` chain from j0 ----
            int jj = j0;
            for (int it = 0; it <= NN; ++it) {
                const int  wsrc = (jj - 1) & 63;
                const bool whi  = jj > 64;
                const int  wva = rl_i(way0, wsrc), wvb = rl_i(way1, wsrc);
                const int  jn  = whi ? wvb : wva;

                int pn; float wn, xn, yn;
                if (jn == 0) {                      // path root: current row
                    pn = i + 1; wn = u_row; xn = qix; yn = qiy;
                } else {
                    const int  s2 = (jn - 1) & 63;
                    const bool h2 = jn > 64;
                    const int   paa = rl_i(p0, s2),   pbb = rl_i(p1, s2);
                    const float waa = rl_f(w0, s2),   wbb = rl_f(w1, s2);
                    const float xaa = rl_f(qcx0, s2), xbb = rl_f(qcx1, s2);
                    const float yaa = rl_f(qcy0, s2), ybb = rl_f(qcy1, s2);
                    pn = h2 ? pbb : paa; wn = h2 ? wbb : waa;
                    xn = h2 ? xbb : xaa; yn = h2 ? ybb : yaa;
                }
                if (col0 == jj) { p0 = pn; w0 = wn; qcx0 = xn; qcy0 = yn; }
                if (col1 == jj) { p1 = pn; w1 = wn; qcx1 = xn; qcy1 = yn; }
                jj = jn;
                if (jj == 0) break;
            }
        }
    }

    // p_[s] = row matched to column col[s]; out[row] = col (0-indexed)
    out[prob * NN + p0 - 1] = col0 - 1;
    out[prob * NN + p1 - 1] = col1 - 1;
}

extern "C" void kernel_launch(void* const* d_in, const int* in_sizes, int n_in,
                              void* d_out, int out_size, void* d_ws, size_t ws_size,
                              hipStream_t stream) {
    const float* preds   = (const float*)d_in[0];   // (4,8,128,2) fp32
    const float* targets = (const float*)d_in[1];   // (4,8,128,2) fp32
    int* out = (int*)d_out;                         // (4,8,128) int32

    hungarian_kernel<<<32, 64, 0, stream>>>(preds, targets, out);
}

// Round 10
// 440.024 us; speedup vs baseline: 1.1027x; 1.1027x over previous
//
#include <hip/hip_runtime.h>

// Hungarian (e-maxx shortest-augmenting-path), 32 independent 128x128 L1
// assignment problems. ONE WAVE per problem, 2 columns per lane, zero LDS,
// zero barriers, bit-exact fp trajectory vs the JAX reference.
//
// R8 WIN (561->494): fused v_min_f32_dpp reduction. R9 WIN (494->466):
// ty-poisoning. R10 FAILED (466->1031): wave is ISSUE-bound (1 instr/cy,
// wave64 VALU=2cy) — never add a second instruction stream. R11 NEUTRAL:
// SALU co-issues free in VALU gaps. R12 WIN (468->398): fill the reduce's
// 6 DPP-hazard slots with body VALU. R13 REGRESSED (398->434): exec-masked
// dual updates — each s_mov_b64 exec + dependent VALU costs ~4-5cy; NEVER
// swap exec in the hot loop. Masked fp updates stay cndmask-td.
// R14 (this round): R12 base + the two SAFE pieces of R13, unbundled:
//   * SALU marks: winner mask from the argmin ballot (bit=1<<src, cselect
//     on hi) — kills 2 v_cmp_eq; poisons = cndmask with SGPR-pair mask.
//   * 7th filler: reduce has 7 hazard gaps; fill all: {j0 mov, cc0, cc1,
//     w0+=td0p, way0, w1+=td1p, way1}. cc compares leave the body (-2
//     VALU); u_row moves to body lag-0 (+1 VALU, flush deleted).
//   * delta application unchanged from R12: vdelta mov + 2 td-cndmask +
//     2 v-subs + 2 minv-subrevs (no exec).
// Net ~-6cy on ~114cy/iter. fp sequence bit-identical to R12/reference.

#define NN 128
#define BIGF 1e9f
#define TYBIG 1e13f

__device__ __forceinline__ int rl_i(int x, int l) {
    return __builtin_amdgcn_readlane(x, l);
}
__device__ __forceinline__ float rl_f(float x, int l) {
    return __uint_as_float((uint32_t)__builtin_amdgcn_readlane((int)__float_as_uint(x), l));
}

// full-wave f32 min -> uniform SGPR result (entry step only).
__device__ __forceinline__ float wave_min_f(float x) {
    int d;
    asm("s_nop 1\n\t"
        "v_min_f32_dpp %1, %1, %1 row_shr:1 row_mask:0xf bank_mask:0xf\n\t"
        "s_nop 1\n\t"
        "v_min_f32_dpp %1, %1, %1 row_shr:2 row_mask:0xf bank_mask:0xf\n\t"
        "s_nop 1\n\t"
        "v_min_f32_dpp %1, %1, %1 row_shr:4 row_mask:0xf bank_mask:0xf\n\t"
        "s_nop 1\n\t"
        "v_min_f32_dpp %1, %1, %1 row_shr:8 row_mask:0xf bank_mask:0xf\n\t"
        "s_nop 1\n\t"
        "v_min_f32_dpp %1, %1, %1 row_bcast:15 row_mask:0xa bank_mask:0xf\n\t"
        "s_nop 1\n\t"
        "v_min_f32_dpp %1, %1, %1 row_bcast:31 row_mask:0xc bank_mask:0xf\n\t"
        "s_nop 1\n\t"
        "v_readlane_b32 %0, %1, 63"
        : "=s"(d), "+v"(x));
    return __uint_as_float((uint32_t)d);
}

// Reduction with ALL 7 hazard slots filled (no s_nop):
//   g0: vj0 = j0 broadcast      (covers m-write -> DPP1 hazard)
//   g1: cc0 = cur0 < minv0_old  (SGPR-pair dest)
//   g2: cc1 = cur1 < minv1_old
//   g3: w0 += td0p              (lag-1 pending)
//   g4: way0 = cc0 ? vj0 : way0 (cc0 written 5 instrs earlier)
//   g5: w1 += td1p
//   g6: way1 = cc1 ? vj0 : way1 (covers DPP6 -> readlane hazard)
// Fillers never touch the DPP register m. Returns delta in SGPR.
__device__ __forceinline__ float wave_min_fill3(
    float m, int j0,
    float cur0, float cur1, float minv0_old, float minv1_old,
    int& way0, int& way1, float& w0, float& w1,
    float td0p, float td1p)
{
    int d, vj0;
    unsigned long long cc0, cc1;
    asm("v_mov_b32 %2, %9\n\t"
        "v_min_f32_dpp %1, %1, %1 row_shr:1 row_mask:0xf bank_mask:0xf\n\t"
        "v_cmp_lt_f32 %7, %10, %12\n\t"
        "v_min_f32_dpp %1, %1, %1 row_shr:2 row_mask:0xf bank_mask:0xf\n\t"
        "v_cmp_lt_f32 %8, %11, %13\n\t"
        "v_min_f32_dpp %1, %1, %1 row_shr:4 row_mask:0xf bank_mask:0xf\n\t"
        "v_add_f32 %5, %14, %5\n\t"
        "v_min_f32_dpp %1, %1, %1 row_shr:8 row_mask:0xf bank_mask:0xf\n\t"
        "v_cndmask_b32 %3, %3, %2, %7\n\t"
        "v_min_f32_dpp %1, %1, %1 row_bcast:15 row_mask:0xa bank_mask:0xf\n\t"
        "v_add_f32 %6, %15, %6\n\t"
        "v_min_f32_dpp %1, %1, %1 row_bcast:31 row_mask:0xc bank_mask:0xf\n\t"
        "v_cndmask_b32 %4, %4, %2, %8\n\t"
        "v_readlane_b32 %0, %1, 63"
        : "=s"(d), "+v"(m), "=&v"(vj0), "+v"(way0), "+v"(way1),
          "+v"(w0), "+v"(w1), "=&s"(cc0), "=&s"(cc1)
        : "s"(j0), "v"(cur0), "v"(cur1), "v"(minv0_old), "v"(minv1_old),
          "v"(td0p), "v"(td1p));
    return __uint_as_float((uint32_t)d);
}

// x = mask ? big : x (v_cndmask with SGPR-pair mask; big pre-hoisted VGPR)
__device__ __forceinline__ void poison(float& x, float big, unsigned long long mk) {
    asm("v_cndmask_b32 %0, %0, %1, %2" : "+v"(x) : "v"(big), "s"(mk));
}

// r = mask ? vdelta : 0 (cndmask with SGPR-pair mask; inline-0 src0)
__device__ __forceinline__ float maskf(float vdelta, unsigned long long mk) {
    float r;
    asm("v_cndmask_b32 %0, 0, %1, %2" : "=v"(r) : "v"(vdelta), "s"(mk));
    return r;
}

__global__ __launch_bounds__(64) void hungarian_kernel(
    const float* __restrict__ preds,
    const float* __restrict__ targets,
    int* __restrict__ out)
{
    const int prob = blockIdx.x;
    const int lane = threadIdx.x;

    const float2* p2 = (const float2*)preds + prob * NN;
    const float2* t2 = (const float2*)targets + prob * NN;

    float2 qav = p2[lane], qbv = p2[lane + 64];
    float2 tav = t2[lane], tbv = t2[lane + 64];
    const float qrx0 = qav.x, qrx1 = qbv.x;
    const float qry0 = qav.y, qry1 = qbv.y;
    const float tx0  = tav.x, tx1  = tbv.x;
    const float ty0  = tav.y, ty1  = tbv.y;

    float v0 = 0.f, v1 = 0.f;       // column duals (reference: start 0)
    float w0 = 0.f, w1 = 0.f;       // u[p[col]] cache (valid when matched)
    float qcx0 = 0.f, qcx1 = 0.f;   // pred x of row p[col]
    float qcy0 = 0.f, qcy1 = 0.f;   // pred y of row p[col]
    int   p0 = 0, p1 = 0;           // matched row (1-indexed), 0 = free
    const int col0 = lane + 1, col1 = lane + 65;

    // hoisted poison constants in VGPRs (VOP3 cndmask can't take literals,
    // and the mask operand uses the single allowed SGPR read)
    float vBIG = BIGF, vTYBIG = TYBIG;
    asm("" : "+v"(vBIG), "+v"(vTYBIG));

    // free-column masks: bit (c-1) of fm0 for cols 1..64, (c-65) of fm1
    unsigned long long fm0 = ~0ull, fm1 = ~0ull;

    for (int i = 0; i < NN; ++i) {
        // coords of current row i (uniform): stable-source readlanes + cselect
        const float qxa = rl_f(qrx0, i & 63), qxb = rl_f(qrx1, i & 63);
        const float qya = rl_f(qry0, i & 63), qyb = rl_f(qry1, i & 63);
        const float qix = (i & 64) ? qxb : qxa;
        const float qiy = (i & 64) ? qyb : qya;

        // ---- specialized first search step: j0 = 0, nothing used ----
        float minv0 = (fabsf(qix - tx0) + fabsf(qiy - ty0)) - v0;
        float minv1 = (fabsf(qix - tx1) + fabsf(qiy - ty1)) - v1;
        int   way0 = 0, way1 = 0;
        float typ0 = ty0, typ1 = ty1;   // poisonable targets-y (reset per row)
        unsigned long long u0m = 0ull, u1m = 0ull;   // used-column masks

        float m     = fminf(minv0, minv1);
        float delta = wave_min_f(m);
        unsigned long long b0 = __ballot(minv0 == delta);
        unsigned long long b1 = __ballot(minv1 == delta);
        bool hi  = (b0 == 0);
        int  src = (int)__ffsll((long long)(hi ? b1 : b0)) - 1;
        int  j1  = src + (hi ? 65 : 1);

        {
            // winner free? (scalar bit test)
            bool freeWin = (((hi ? fm1 : fm0) >> src) & 1ull) != 0;
            // stable-source fetch of matched-row data of winner column
            float u_j0 = rl_f(hi ? w1 : w0, src);
            float cqx  = rl_f(hi ? qcx1 : qcx0, src);
            float cqy  = rl_f(hi ? qcy1 : qcy0, src);

            // step-0 updates: nothing used -> v,w unchanged; minv -= delta
            minv0 -= delta;
            minv1 -= delta;
            float u_row = delta;          // u[i+1] = 0 + delta (exact)
            int   j0    = j1;

            if (!freeWin) {
                float td0p = 0.f, td1p = 0.f;   // lag-1 w pendings (+0 no-op)

                for (int it = 0; it < NN + 2; ++it) {
                    // mark used[j0]: winner mask straight from the carried
                    // ballot (bit src of half hi) — pure SALU.
                    const unsigned long long bit = 1ull << src;
                    const unsigned long long mk0m = hi ? 0ull : bit;
                    const unsigned long long mk1m = hi ? bit : 0ull;
                    u0m |= mk0m; u1m |= mk1m;
                    poison(minv0, vBIG,   mk0m);
                    poison(minv1, vBIG,   mk1m);
                    poison(typ0,  vTYBIG, mk0m);
                    poison(typ1,  vTYBIG, mk1m);

                    // used cols: cur == 1e13 exactly (> any minv); unused:
                    // bit-exact reference reduced cost
                    const float cur0 = ((fabsf(cqx - tx0) + fabsf(cqy - typ0)) - u_j0) - v0;
                    const float cur1 = ((fabsf(cqx - tx1) + fabsf(cqy - typ1)) - u_j0) - v1;

                    // minv update (pre-update copies feed the slotted
                    // cc-compares inside the reduce)
                    const float m0o = minv0, m1o = minv1;
                    minv0 = fminf(cur0, minv0);
                    minv1 = fminf(cur1, minv1);
                    m = fminf(minv0, minv1);

                    // reduce; slots: cc cmps, way cndmasks, lag-1 w adds
                    delta = wave_min_fill3(m, j0, cur0, cur1, m0o, m1o,
                                           way0, way1, w0, w1, td0p, td1p);

                    b0 = __ballot(minv0 == delta);
                    b1 = __ballot(minv1 == delta);
                    hi  = (b0 == 0);
                    src = (int)__ffsll((long long)(hi ? b1 : b0)) - 1;
                    j1  = src + (hi ? 65 : 1);

                    // terminate if winner is a free column (scalar bit test)
                    const bool term = (((hi ? fm1 : fm0) >> src) & 1ull) != 0;
                    const float u_nn = rl_f(hi ? w1 : w0, src);
                    const float nqx  = rl_f(hi ? qcx1 : qcx0, src);
                    const float nqy  = rl_f(hi ? qcy1 : qcy0, src);

                    // reference-exact dual updates (R12 scheme, NO exec):
                    // td = used ? delta : 0 (cndmask); v -= td now; w += td
                    // lag-1 via slots; minv -= delta; u_row += delta lag-0
                    const float td0 = maskf(delta, u0m);
                    const float td1 = maskf(delta, u1m);
                    v0 -= td0;
                    v1 -= td1;
                    minv0 -= delta;
                    minv1 -= delta;
                    u_row += delta;
                    td0p = td0; td1p = td1;

                    j0 = j1; u_j0 = u_nn; cqx = nqx; cqy = nqy;
                    if (term) break;
                }

                // flush the final iteration's pending w adds
                w0 += td0p;
                w1 += td1p;
            }

            // the terminating col j0 leaves the free set (once per row)
            {
                const unsigned long long mkb = 1ull << ((j0 - 1) & 63);
                if (j0 > 64) fm1 &= ~mkb; else fm0 &= ~mkb;
            }

            // ---- augment: shuffle (p, w, qc) along `way` chain from j0 ----
            int jj = j0;
            for (int it = 0; it <= NN; ++it) {
                const int  wsrc = (jj - 1) & 63;
                const bool whi  = jj > 64;
                const int  wva = rl_i(way0, wsrc), wvb = rl_i(way1, wsrc);
                const int  jn  = whi ? wvb : wva;

                int pn; float wn, xn, yn;
                if (jn == 0) {                      // path root: current row
                    pn = i + 1; wn = u_row; xn = qix; yn = qiy;
                } else {
                    const int  s2 = (jn - 1) & 63;
                    const bool h2 = jn > 64;
                    const int   paa = rl_i(p0, s2),   pbb = rl_i(p1, s2);
                    const float waa = rl_f(w0, s2),   wbb = rl_f(w1, s2);
                    const float xaa = rl_f(qcx0, s2), xbb = rl_f(qcx1, s2);
                    const float yaa = rl_f(qcy0, s2), ybb = rl_f(qcy1, s2);
                    pn = h2 ? pbb : paa; wn = h2 ? wbb : waa;
                    xn = h2 ? xbb : xaa; yn = h2 ? ybb : yaa;
                }
                if (col0 == jj) { p0 = pn; w0 = wn; qcx0 = xn; qcy0 = yn; }
                if (col1 == jj) { p1 = pn; w1 = wn; qcx1 = xn; qcy1 = yn; }
                jj = jn;
                if (jj == 0) break;
            }
        }
    }

    // p_[s] = row matched to column col[s]; out[row] = col (0-indexed)
    out[prob * NN + p0 - 1] = col0 - 1;
    out[prob * NN + p1 - 1] = col1 - 1;
}

extern "C" void kernel_launch(void* const* d_in, const int* in_sizes, int n_in,
                              void* d_out, int out_size, void* d_ws, size_t ws_size,
                              hipStream_t stream) {
    const float* preds   = (const float*)d_in[0];   // (4,8,128,2) fp32
    const float* targets = (const float*)d_in[1];   // (4,8,128,2) fp32
    int* out = (int*)d_out;                         // (4,8,128) int32

    hungarian_kernel<<<32, 64, 0, stream>>>(preds, targets, out);
}